// Round 6
// baseline (210.969 us; speedup 1.0000x reference)
//
#include <hip/hip_runtime.h>

// YOLO loss. B=32, H=W=32, A=9, C=80, T=50, NET=512.
// Each wave owns 16 cells (5440 B/array, 16B-aligned). Stage: dense aligned
// dwordx4 stream loads -> scatter into pad-88 LDS tile (aligned b128 reads,
// bank-spread rows). Compute: 4 lanes/cell (R5's verified logic), box fields
// via broadcast LDS reads. No __syncthreads. Grid = 4608 blocks x 256.

constexpr int NT  = 50;
constexpr int PAD = 88;                 // 85 -> 88: rows stay 16B-aligned
typedef __attribute__((ext_vector_type(4))) float f4;

__global__ __launch_bounds__(256) void yolo_loss_kernel(
    const float* __restrict__ y_pred,     // (B,H,W,A,85) flat
    const float* __restrict__ y_true,     // (B,H,W,A,85)
    const float* __restrict__ true_boxes, // (B,50,4)
    const float* __restrict__ anchors,    // (9,2)
    float* __restrict__ out)              // (B,)
{
    __shared__ float sP[4][16 * PAD];     // 22528 B
    __shared__ float sT[4][16 * PAD];     // 22528 B
    __shared__ f4    s_box[4][NT];        // 3200 B
    __shared__ float s_area[4][NT];       // 800 B

    const int tid  = threadIdx.x;
    const int lane = tid & 63;
    const int wid  = tid >> 6;

    const int cellW = blockIdx.x * 64 + wid * 16;   // wave's first cell
    const int b     = (blockIdx.x * 64) / 9216;     // 144 blocks per image

    // ---- issue ALL global loads up front (aligned, dense, independent) ----
    const f4* gp4 = (const f4*)__builtin_assume_aligned(y_pred + (size_t)cellW * 85, 16);
    const f4* gt4 = (const f4*)__builtin_assume_aligned(y_true + (size_t)cellW * 85, 16);

    const f4 cp0 = gp4[lane];        const f4 ct0 = gt4[lane];
    const f4 cp1 = gp4[lane + 64];   const f4 ct1 = gt4[lane + 64];
    const f4 cp2 = gp4[lane + 128];  const f4 ct2 = gt4[lane + 128];
    const f4 cp3 = gp4[lane + 192];  const f4 ct3 = gt4[lane + 192];
    const f4 cp4 = gp4[lane + 256];  const f4 ct4 = gt4[lane + 256];
    f4 cp5 = {0.f,0.f,0.f,0.f}, ct5 = {0.f,0.f,0.f,0.f};
    if (lane < 20) { cp5 = gp4[lane + 320]; ct5 = gt4[lane + 320]; }

    f4 tb = {0.f,0.f,0.f,0.f};
    if (lane < NT) {
        const f4* tbp = (const f4*)__builtin_assume_aligned(true_boxes + (size_t)b * NT * 4, 16);
        tb = tbp[lane];
    }

    // ---- scatter: chunk c covers dwords q=4c..4c+3 of the 1360-dword span;
    //      g = q0/85 via magic (exact for q0<1360), field f0 = q0%85.
    //      Crossing a cell boundary bumps by PAD-85 = 3. ----
    float* wP = sP[wid];
    float* wT = sT[wid];
    auto scatter = [](float* base, f4 v, int c) {
        const int q0 = 4 * c;
        const int g  = (q0 * 49345) >> 22;
        const int f0 = q0 - 85 * g;
        float* d = base + g * PAD + f0;
        d[0] = v[0];
        d[1 + (f0 >= 84 ? 3 : 0)] = v[1];
        d[2 + (f0 >= 83 ? 3 : 0)] = v[2];
        d[3 + (f0 >= 82 ? 3 : 0)] = v[3];
    };
    scatter(wP, cp0, lane);        scatter(wT, ct0, lane);
    scatter(wP, cp1, lane + 64);   scatter(wT, ct1, lane + 64);
    scatter(wP, cp2, lane + 128);  scatter(wT, ct2, lane + 128);
    scatter(wP, cp3, lane + 192);  scatter(wT, ct3, lane + 192);
    scatter(wP, cp4, lane + 256);  scatter(wT, ct4, lane + 256);
    if (lane < 20) { scatter(wP, cp5, lane + 320); scatter(wT, ct5, lane + 320); }

    // ---- per-wave IoU table ----
    if (lane < NT) {
        const float tx = tb[0] * (1.0f / 32.0f);
        const float ty = tb[1] * (1.0f / 32.0f);
        const float tw = tb[2] * (1.0f / 512.0f);
        const float th = tb[3] * (1.0f / 512.0f);
        f4 e;
        e[0] = tx - tw * 0.5f;  e[1] = tx + tw * 0.5f;
        e[2] = ty - th * 0.5f;  e[3] = ty + th * 0.5f;
        s_box[wid][lane]  = e;
        s_area[wid][lane] = tw * th;
    }

    // wave-local fence: all ds_writes done before any ds_read; memory clobber
    // stops the compiler reordering LDS reads above this point.
    asm volatile("s_waitcnt lgkmcnt(0)" ::: "memory");

    // ---- compute: 4 lanes per cell ----
    const int s = lane & 3;
    const int g = lane >> 2;

    const int cell  = cellW + g;
    const int local = cell - b * 9216;
    const int a = local % 9;
    const int w = (local / 9) % 32;
    const int h = local / 288;

    const float* cP = wP + g * PAD;
    const float* cT = wT + g * PAD;

    // box fields: broadcast reads (4 lanes of a group hit the same address)
    const f4 pb  = *(const f4*)cP;
    const f4 tbx = *(const f4*)cT;
    const float p4v = cP[4], t4v = cT[4];

    // class slices: lane s owns fields 16j+4s+e (aligned b128 reads)
    const f4 pv0 = *(const f4*)(cP + 4 * s);
    const f4 pv1 = *(const f4*)(cP + 16 + 4 * s);
    const f4 pv2 = *(const f4*)(cP + 32 + 4 * s);
    const f4 pv3 = *(const f4*)(cP + 48 + 4 * s);
    const f4 pv4 = *(const f4*)(cP + 64 + 4 * s);
    const f4 tv0 = *(const f4*)(cT + 4 * s);
    const f4 tv1 = *(const f4*)(cT + 16 + 4 * s);
    const f4 tv2 = *(const f4*)(cT + 32 + 4 * s);
    const f4 tv3 = *(const f4*)(cT + 48 + 4 * s);
    const f4 tv4 = *(const f4*)(cT + 64 + 4 * s);
    f4 pt = {0.f,0.f,0.f,0.f}, ttl = {0.f,0.f,0.f,0.f};
    float p84 = 0.f, t84 = 0.f;
    if (s == 0) { pt  = *(const f4*)(cP + 80); ttl = *(const f4*)(cT + 80); }
    if (s == 1) { p84 = cP[84]; t84 = cT[84]; }

    const float aw = anchors[a * 2 + 0];
    const float ah = anchors[a * 2 + 1];

    // ---- geometry (group-uniform, redundant on 4 lanes) ----
    const float p0 = pb[0], p1 = pb[1], p2 = pb[2], p3 = pb[3], p4 = p4v;
    const float t0 = tbx[0], t1 = tbx[1], t2 = tbx[2], t3 = tbx[3], t4 = t4v;

    const float sig0  = 1.0f / (1.0f + __expf(-p0));
    const float sig1  = 1.0f / (1.0f + __expf(-p1));
    const float predx = (float)w + sig0;
    const float predy = (float)h + sig1;
    const float pconf = 1.0f / (1.0f + __expf(-p4));

    const float px = predx * (1.0f / 32.0f);
    const float py = predy * (1.0f / 32.0f);
    const float pw = __expf(p2) * aw * (1.0f / 512.0f);
    const float ph = __expf(p3) * ah * (1.0f / 512.0f);
    const float pminx = px - pw * 0.5f, pmaxx = px + pw * 0.5f;
    const float pminy = py - ph * 0.5f, pmaxy = py + ph * 0.5f;
    const float parea = pw * ph;

    // ---- IoU ignore flag (boxes 4i+s per lane) ----
    int ig = 0;
    #pragma unroll
    for (int i = 0; i < 13; ++i) {
        const int box = 4 * i + s;
        if (box < NT) {
            const f4 e = s_box[wid][box];
            float iw = fminf(pmaxx, e[1]) - fmaxf(pminx, e[0]);
            float ih = fminf(pmaxy, e[3]) - fmaxf(pminy, e[2]);
            iw = fmaxf(iw, 0.0f);
            ih = fmaxf(ih, 0.0f);
            const float inter = iw * ih;
            const float uni   = parea + s_area[wid][box] - inter;
            ig |= (2.0f * inter >= uni) ? 1 : 0;
        }
    }

    // ---- classes pass 1: argmax(true) carrying pred, and max(pred) ----
    float tmax = -1e30f, p_at = 0.0f, pmax = -1e30f;
    int   tidx = 1 << 20;
#define STEP1(PV, TV, J, E) {                                              \
        const bool cls = ((J) > 0) || (4 * s + (E) >= 5);                  \
        const float tcm = cls ? (TV)[(E)] : -1e30f;                        \
        const float pc  = (PV)[(E)];                                       \
        if (tcm > tmax) { tmax = tcm; p_at = pc; tidx = 16*(J)+4*s+(E); }  \
        pmax = fmaxf(pmax, cls ? pc : -1e30f); }
#define SLICE1(PV, TV, J) STEP1(PV,TV,J,0) STEP1(PV,TV,J,1) STEP1(PV,TV,J,2) STEP1(PV,TV,J,3)
    SLICE1(pv0, tv0, 0) SLICE1(pv1, tv1, 1) SLICE1(pv2, tv2, 2)
    SLICE1(pv3, tv3, 3) SLICE1(pv4, tv4, 4)
#define TAIL1(E) {                                                         \
        const float tcm = (s == 0) ? ttl[(E)] : -1e30f;                    \
        if (tcm > tmax) { tmax = tcm; p_at = pt[(E)]; tidx = 80 + (E); }   \
        pmax = fmaxf(pmax, (s == 0) ? pt[(E)] : -1e30f); }
    TAIL1(0) TAIL1(1) TAIL1(2) TAIL1(3)
    {
        const float tcm = (s == 1) ? t84 : -1e30f;
        if (tcm > tmax) { tmax = tcm; p_at = p84; tidx = 84; }
        pmax = fmaxf(pmax, (s == 1) ? p84 : -1e30f);
    }

    // combine across the 4 lanes of the group
    #pragma unroll
    for (int d = 1; d <= 2; d <<= 1) {
        const float ot = __shfl_xor(tmax, d);
        const float op = __shfl_xor(p_at, d);
        const int   oi = __shfl_xor(tidx, d);
        const bool upd = (ot > tmax) || (ot == tmax && oi < tidx);
        tmax = upd ? ot : tmax;
        p_at = upd ? op : p_at;
        tidx = upd ? oi : tidx;
        pmax = fmaxf(pmax, __shfl_xor(pmax, d));
        ig  |= __shfl_xor(ig, d);
    }

    // ---- classes pass 2: sum exp(pred - pmax), 4 accumulator streams ----
    f4 acc = {0.f, 0.f, 0.f, 0.f};
#define STEP2(PV, J, E) {                                                  \
        const bool cls = ((J) > 0) || (4 * s + (E) >= 5);                  \
        acc[(E)] += cls ? __expf((PV)[(E)] - pmax) : 0.0f; }
#define SLICE2(PV, J) STEP2(PV,J,0) STEP2(PV,J,1) STEP2(PV,J,2) STEP2(PV,J,3)
    SLICE2(pv0, 0) SLICE2(pv1, 1) SLICE2(pv2, 2) SLICE2(pv3, 3) SLICE2(pv4, 4)
    #pragma unroll
    for (int e = 0; e < 4; ++e)
        acc[e] += (s == 0) ? __expf(pt[e] - pmax) : 0.0f;
    acc[0] += (s == 1) ? __expf(p84 - pmax) : 0.0f;

    float sum = (acc[0] + acc[1]) + (acc[2] + acc[3]);
    sum += __shfl_xor(sum, 1);
    sum += __shfl_xor(sum, 2);
    const float ce = (pmax + __logf(sum)) - p_at;

    // ---- deltas ----
    const float om  = t4;
    const float ew  = __expf(t2) * aw * (1.0f / 512.0f);
    const float eh  = __expf(t3) * ah * (1.0f / 512.0f);
    const float whs = 2.0f - ew * eh;

    const float xyd0 = om * (predx - t0) * whs;
    const float xyd1 = om * (predy - t1) * whs;
    const float whd0 = om * (p2 - t2) * whs;
    const float whd1 = om * (p3 - t3) * whs;
    const float cd   = om * (pconf - t4) * 5.0f + (1.0f - om) * (ig ? 0.0f : pconf);

    float partial = xyd0 * xyd0 + xyd1 * xyd1 + whd0 * whd0 + whd1 * whd1 +
                    cd * cd + om * ce;

    // ---- wave-level sum of the 16 group leaders; one atomic per wave ----
    partial = (s == 0) ? partial : 0.0f;
    partial += __shfl_xor(partial, 4);
    partial += __shfl_xor(partial, 8);
    partial += __shfl_xor(partial, 16);
    partial += __shfl_xor(partial, 32);
    if (lane == 0)
        atomicAdd(&out[b], partial);
}

extern "C" void kernel_launch(void* const* d_in, const int* in_sizes, int n_in,
                              void* d_out, int out_size, void* d_ws, size_t ws_size,
                              hipStream_t stream) {
    // setup_inputs order: input_image (unused), y_pred, y_true, true_boxes, anchors
    const float* y_pred     = (const float*)d_in[1];
    const float* y_true     = (const float*)d_in[2];
    const float* true_boxes = (const float*)d_in[3];
    const float* anchors    = (const float*)d_in[4];
    float* out = (float*)d_out;

    hipMemsetAsync(d_out, 0, (size_t)out_size * sizeof(float), stream);

    dim3 grid(294912 / 64);   // 4608 blocks, 64 cells each (16 per wave)
    yolo_loss_kernel<<<grid, 256, 0, stream>>>(y_pred, y_true, true_boxes, anchors, out);
}